// Round 14
// baseline (258.619 us; speedup 1.0000x reference)
//
#include <hip/hip_runtime.h>
#include <math.h>

#define BB 512       // batch rows (M)
#define DD 512       // depth (K)
#define CC 100000    // classes (N)
#define MARGIN2 0.5f
#define PI_F 3.14159265358979323846f

#define BM 128
#define BN 128
#define KSTEPS 8             // K = 8 x 64
#define NPAN 782             // ceil(100000/128), last panel 32 cols
#define GRID (4 * NPAN)      // 3128 = 8 * 391 exactly

typedef __bf16 bf16x8 __attribute__((ext_vector_type(8)));
typedef float f32x4 __attribute__((ext_vector_type(4)));

static __device__ __forceinline__ unsigned short f2bf(float f) {
    union { float f; unsigned u; } v; v.f = f;
    unsigned r = v.u + 0x7FFFu + ((v.u >> 16) & 1u);   // round-to-nearest-even
    return (unsigned short)(r >> 16);
}

// ---------------- K1: row-normalize x -> bf16 (plain row-major) ----------------
__global__ __launch_bounds__(256) void k_norm_x(const float* __restrict__ x,
                                                unsigned short* __restrict__ xnb) {
    const int lane = threadIdx.x & 63;
    const int row  = blockIdx.x * 4 + (threadIdx.x >> 6);
    const float* xr = x + (size_t)row * DD;
    float4 v0 = *(const float4*)(xr + lane * 4);
    float4 v1 = *(const float4*)(xr + lane * 4 + 256);
    float s = v0.x*v0.x + v0.y*v0.y + v0.z*v0.z + v0.w*v0.w
            + v1.x*v1.x + v1.y*v1.y + v1.z*v1.z + v1.w*v1.w;
    #pragma unroll
    for (int m = 32; m; m >>= 1) s += __shfl_xor(s, m, 64);
    float rs = rsqrtf(fmaxf(s, 1e-12f));
    ushort4 o0, o1;
    o0.x = f2bf(v0.x * rs); o0.y = f2bf(v0.y * rs);
    o0.z = f2bf(v0.z * rs); o0.w = f2bf(v0.w * rs);
    o1.x = f2bf(v1.x * rs); o1.y = f2bf(v1.y * rs);
    o1.z = f2bf(v1.z * rs); o1.w = f2bf(v1.w * rs);
    *(ushort4*)(xnb + (size_t)row * DD + lane * 4)       = o0;
    *(ushort4*)(xnb + (size_t)row * DD + lane * 4 + 256) = o1;
}

// ---------------- K2: bf16 MFMA GEMM, barrier-free free-running K-loop ----------
// No LDS, no barriers, no waitcnt asm in the K loop. 512 thr / 8 waves of 64x32.
// A frags straight from L2-resident xnb (16B/lane, 64B segments); B frags as
// 8 same-column f32 loads (4x64B segments/instr) + cvt_pk in-register. Waves
// free-run; compiler software-pipelines the unrolled K loop under the 128-reg
// budget (acc 32 + af 32 + b 32 + addr ~20). LDS (17KB) only for the post-loop
// column-norm reduce and the sector-aligned NT epilogue.
#define LDSZ (16896 + 512)

__global__ __launch_bounds__(512, 4) void k_gemm(const unsigned short* __restrict__ xnb,
                                                 const float* __restrict__ W,
                                                 float* __restrict__ out) {
    __shared__ __align__(16) unsigned char LDS[LDSZ];
    float* rn = (float*)(LDS + 16896);

    const int tid = threadIdx.x;
    const int bid = blockIdx.x;

    // bijective XCD swizzle: 3128 = 8*391; 4 mb-sharers of a W panel -> same XCD L2
    const int v  = (bid & 7) * 391 + (bid >> 3);
    const int mb = v & 3;
    const int nb = v >> 2;
    const int M0 = mb * BM;
    const int N0 = nb * BN;

    const int lane = tid & 63;
    const int wid  = tid >> 6;     // 0..7
    const int wm = wid >> 2;       // 0..1 -> 64 rows each
    const int wn = wid & 3;        // 0..3 -> 32 cols each
    const int lr = lane & 15;
    const int lg = lane >> 4;

    // A element indices (32-bit, saddr+voffset form): row*DD + lg*8
    unsigned aidx[4];
    #pragma unroll
    for (int mf = 0; mf < 4; ++mf)
        aidx[mf] = (unsigned)((M0 + wm * 64 + mf * 16 + lr) * DD + lg * 8);

    // B element indices: col + lg*8*CC (k-low part folded per-lane)
    unsigned bidx[2];
    #pragma unroll
    for (int nf = 0; nf < 2; ++nf) {
        int col = N0 + wn * 32 + nf * 16 + lr;
        col = col < CC ? col : CC - 1;         // tail-panel clamp (dead cols)
        bidx[nf] = (unsigned)(col + lg * 8 * CC);
    }

    float bq0 = 0.f, bq1 = 0.f;                // column sumsq (wm==0 waves only)

    f32x4 acc[4][2];
    #pragma unroll
    for (int mf = 0; mf < 4; ++mf)
        #pragma unroll
        for (int nf = 0; nf < 2; ++nf)
            acc[mf][nf] = (f32x4)0.f;

    #pragma unroll
    for (int t = 0; t < KSTEPS; ++t) {
        // ---- A fragments: 8 x 16B direct loads ----
        bf16x8 af[4][2];
        #pragma unroll
        for (int ks = 0; ks < 2; ++ks)
            #pragma unroll
            for (int mf = 0; mf < 4; ++mf)
                af[mf][ks] = *(const bf16x8*)(xnb + aidx[mf] + t * 64 + ks * 32);

        // ---- B fragments: 32 x 4B direct loads (per-lane column strided) ----
        float b[2][2][8];
        #pragma unroll
        for (int nf = 0; nf < 2; ++nf)
            #pragma unroll
            for (int ks = 0; ks < 2; ++ks)
                #pragma unroll
                for (int j = 0; j < 8; ++j)
                    b[nf][ks][j] = W[bidx[nf] + (unsigned)((t * 64 + ks * 32 + j) * CC)];

        // ---- fused column sumsq (each element exactly once: wm==0 only) ----
        if (wm == 0) {
            #pragma unroll
            for (int ks = 0; ks < 2; ++ks)
                #pragma unroll
                for (int j = 0; j < 8; ++j) {
                    bq0 += b[0][ks][j] * b[0][ks][j];
                    bq1 += b[1][ks][j] * b[1][ks][j];
                }
        }

        // ---- cvt to bf16 + 16 MFMA ----
        #pragma unroll
        for (int ks = 0; ks < 2; ++ks) {
            bf16x8 bf[2];
            #pragma unroll
            for (int nf = 0; nf < 2; ++nf) {
                union { unsigned u[4]; bf16x8 v; } p;
                asm("v_cvt_pk_bf16_f32 %0, %1, %2" : "=v"(p.u[0]) : "v"(b[nf][ks][0]), "v"(b[nf][ks][1]));
                asm("v_cvt_pk_bf16_f32 %0, %1, %2" : "=v"(p.u[1]) : "v"(b[nf][ks][2]), "v"(b[nf][ks][3]));
                asm("v_cvt_pk_bf16_f32 %0, %1, %2" : "=v"(p.u[2]) : "v"(b[nf][ks][4]), "v"(b[nf][ks][5]));
                asm("v_cvt_pk_bf16_f32 %0, %1, %2" : "=v"(p.u[3]) : "v"(b[nf][ks][6]), "v"(b[nf][ks][7]));
                bf[nf] = p.v;
            }
            #pragma unroll
            for (int mf = 0; mf < 4; ++mf)
                #pragma unroll
                for (int nf = 0; nf < 2; ++nf)
                    acc[mf][nf] = __builtin_amdgcn_mfma_f32_16x16x32_bf16(
                        bf[nf], af[mf][ks], acc[mf][nf], 0, 0, 0);
        }
    }

    // ---- deterministic column-norm reduction: part[col][lg], unique owners ----
    float* part = (float*)LDS;                 // [128][4] floats = 2KB
    __syncthreads();                           // (harmless; orders LDS reuse)
    if (wm == 0) {
        part[(wn * 32 + lr) * 4 + lg]      = bq0;
        part[(wn * 32 + 16 + lr) * 4 + lg] = bq1;
    }
    __syncthreads();
    if (tid < BN) {
        float s = part[tid * 4] + part[tid * 4 + 1]
                + part[tid * 4 + 2] + part[tid * 4 + 3];   // fixed order
        rn[tid] = rsqrtf(fmaxf(s, 1e-12f));
    }
    __syncthreads();

    // ---- epilogue: LDS-staged -> 512B-aligned full-sector non-temporal stores ----
    float* stag = (float*)LDS;                 // 32 rows x 132 floats = 16.9KB
    #pragma unroll
    for (int rd = 0; rd < 4; ++rd) {
        if (wm == (rd >> 1)) {
            #pragma unroll
            for (int f = 0; f < 2; ++f) {
                const int mf = (rd & 1) * 2 + f;
                const int ml = f * 16 + lr;
                #pragma unroll
                for (int nf = 0; nf < 2; ++nf) {
                    const int nl = wn * 32 + nf * 16 + lg * 4;
                    const f32x4 rn4 = *(const f32x4*)(rn + nl);
                    f32x4 o;
                    #pragma unroll
                    for (int r = 0; r < 4; ++r)
                        o[r] = acc[mf][nf][r] * rn4[r];
                    *(f32x4*)(stag + ml * 132 + nl) = o;
                }
            }
        }
        __syncthreads();
        #pragma unroll
        for (int j = tid; j < 1024; j += 512) {
            const int m = j >> 5;
            const int n = (j & 31) * 4;
            if (N0 + n + 4 <= CC) {
                f32x4 o = *(const f32x4*)(stag + m * 132 + n);
                __builtin_nontemporal_store(o,
                    (f32x4*)(out + (size_t)(M0 + rd * 32 + m) * CC + N0 + n));
            }
        }
        __syncthreads();
    }
}

// ---------------- K3: margin fixup at label positions ----------------
__global__ __launch_bounds__(512) void k_fix(const int* __restrict__ lab,
                                             float* __restrict__ out) {
    const int b = threadIdx.x;
    const int c = lab[b];
    const size_t idx = (size_t)b * CC + c;
    float t = out[idx];
    t = fminf(fmaxf(t, -1.f), 1.f);
    float th = acosf(t) + MARGIN2;
    th = fminf(th, PI_F);              // min(t, t + (pi - stopgrad(t))) value-wise
    out[idx] = cosf(th);               // M3 == 0: no additive term
}

extern "C" void kernel_launch(void* const* d_in, const int* in_sizes, int n_in,
                              void* d_out, int out_size, void* d_ws, size_t ws_size,
                              hipStream_t stream) {
    const float* x   = (const float*)d_in[0];
    const float* W   = (const float*)d_in[1];
    const int*   lab = (const int*)d_in[2];
    float* out = (float*)d_out;

    unsigned short* xnb = (unsigned short*)d_ws;   // 512*512*2 = 512 KB scratch

    k_norm_x<<<dim3(BB / 4), dim3(256), 0, stream>>>(x, xnb);
    k_gemm<<<dim3(GRID), dim3(512), 0, stream>>>(xnb, W, out);
    k_fix<<<dim3(1), dim3(512), 0, stream>>>(lab, out);
}

// Round 15
// 112.123 us; speedup vs baseline: 2.3066x; 2.3066x over previous
//
#include <hip/hip_runtime.h>
#include <math.h>

#define BB 512       // batch rows (M)
#define DD 512       // depth (K)
#define CC 100000    // classes (N)
#define MARGIN2 0.5f
#define PI_F 3.14159265358979323846f

#define BM 128
#define BN 128
#define BK 64
#define KSTEPS (DD / BK)     // 8
#define NPAN 782             // ceil(100000/128), last panel 32 cols
#define GRID (4 * NPAN)      // 3128 = 8 * 391 exactly

typedef __bf16 bf16x8 __attribute__((ext_vector_type(8)));
typedef float f32x4 __attribute__((ext_vector_type(4)));

static __device__ __forceinline__ unsigned short f2bf(float f) {
    union { float f; unsigned u; } v; v.f = f;
    unsigned r = v.u + 0x7FFFu + ((v.u >> 16) & 1u);   // round-to-nearest-even
    return (unsigned short)(r >> 16);
}

// swizzled LDS byte offset for row-major [row][64 x bf16] tiles (row stride 128B)
static __device__ __forceinline__ int swz(int row, int kbyte) {
    return row * 128 + (kbyte ^ ((row & 7) << 4));
}

// async global->LDS, 16B per lane; LDS dest = wave-uniform base + lane*16 (HW rule)
static __device__ __forceinline__ void gll16(const unsigned char* g, unsigned char* l) {
    __builtin_amdgcn_global_load_lds(
        (const __attribute__((address_space(1))) void*)g,
        (__attribute__((address_space(3))) void*)l, 16, 0, 0);
}

// ---------------- K1: row-normalize x -> bf16, PRE-SWIZZLED A images ----------------
// Image layout for BM=128: img[(mb*8 + t)*16384 + swz(lrow, c8*16) + sub*8],
// mb = row>>7, lrow = row&127 -> gemm's linear global_load_lds reproduces the
// swizzled Ash layout exactly (m173 pattern).
__global__ __launch_bounds__(256) void k_norm_x(const float* __restrict__ x,
                                                unsigned char* __restrict__ img) {
    const int lane = threadIdx.x & 63;
    const int row  = blockIdx.x * 4 + (threadIdx.x >> 6);
    const float* xr = x + (size_t)row * DD;
    float4 v0 = *(const float4*)(xr + lane * 4);
    float4 v1 = *(const float4*)(xr + lane * 4 + 256);
    float s = v0.x*v0.x + v0.y*v0.y + v0.z*v0.z + v0.w*v0.w
            + v1.x*v1.x + v1.y*v1.y + v1.z*v1.z + v1.w*v1.w;
    #pragma unroll
    for (int m = 32; m; m >>= 1) s += __shfl_xor(s, m, 64);
    float rs = rsqrtf(fmaxf(s, 1e-12f));
    ushort4 o0, o1;
    o0.x = f2bf(v0.x * rs); o0.y = f2bf(v0.y * rs);
    o0.z = f2bf(v0.z * rs); o0.w = f2bf(v0.w * rs);
    o1.x = f2bf(v1.x * rs); o1.y = f2bf(v1.y * rs);
    o1.z = f2bf(v1.z * rs); o1.w = f2bf(v1.w * rs);

    const int mb   = row >> 7;            // which 128-row M block (0..3)
    const int lrow = row & 127;
    const int k0   = lane * 4;            // v0 covers k0..k0+3; v1 covers k0+256..
    const int t0   = k0 >> 6;             // 0..3 (v1 -> t0+4)
    const int c8   = (k0 >> 3) & 7;       // 16B chunk within 128B row
    const int sub  = (k0 >> 2) & 1;       // 8B half of the chunk
    const int base = (mb * 8 + t0) * 16384 + lrow * 128
                   + ((c8 * 16) ^ ((lrow & 7) << 4)) + sub * 8;
    *(ushort4*)(img + base)         = o0;
    *(ushort4*)(img + base + 65536) = o1;    // t0+4 image (4 * 16384)
}

// ---------------- K2: bf16 MFMA GEMM, 128x128, depth-3 B + conflict-free writes ----
// 512 threads / 8 waves of 64x32 (acc = 32 AGPR). Regs ~110 <= 128 -> 4 waves/SIMD;
// LDS 64.5KB -> 2 blocks/CU -> 16 waves/CU.
// B staging task = (k-octet o, column n): 8 same-column fp32 loads (lane-coalesced),
// 4x cvt_pk, ONE ds_write_b128 at n*128 + (o*16 ^ ((n&7)<<4)) -> 8-lane groups tile
// all 32 banks -> ZERO write conflicts (R14 evidence: R12's 3.2M conflicts = B writes).
// Depth-3 f rotation: B(T+3) issued at iter T, packed at T+2 -> pack never blocks;
// end-of-iter vmcnt(16) forces B(T+2) after ~1.3 iters of cover (HBM-miss tail).
#define ABUF 16384
#define LDSZ (2 * ABUF + 2 * 16384 + 512)   // 66048 -> 2 blocks/CU

__global__ __launch_bounds__(512, 4) void k_gemm(const unsigned char* __restrict__ img,
                                                 const float* __restrict__ W,
                                                 float* __restrict__ out) {
    __shared__ __align__(16) unsigned char LDS[LDSZ];
    unsigned char* bufA = LDS;                  // 2 x 16KB
    unsigned char* bufB = LDS + 2 * ABUF;       // 2 x 16KB
    float* rn = (float*)(LDS + 2 * ABUF + 32768);

    const int tid = threadIdx.x;
    const int bid = blockIdx.x;

    // bijective XCD swizzle: 3128 = 8*391; 4 mb-sharers of a W panel -> same XCD L2
    const int v  = (bid & 7) * 391 + (bid >> 3);
    const int mb = v & 3;
    const int nb = v >> 2;
    const int M0 = mb * BM;
    const int N0 = nb * BN;

    const int lane = tid & 63;
    const int wid  = tid >> 6;     // 0..7
    const int wm = wid >> 2;       // 0..1 -> 64 rows each
    const int wn = wid & 3;        // 0..3 -> 32 cols each
    const int lr = lane & 15;
    const int lg = lane >> 4;

    // ---- B staging tasks: 2 per thread; s = o*128 + n (o = k-octet 0..7) ----
    int b_go[2], b_ld[2];
    #pragma unroll
    for (int i = 0; i < 2; ++i) {
        int s  = tid + i * 512;
        int n  = s & 127;
        int o  = s >> 7;                       // k-octet
        int col = N0 + n;
        col = col < CC ? col : CC - 1;         // tail-panel clamp (dead cols)
        b_go[i] = o * 8 * CC + col;
        b_ld[i] = n * 128 + ((o * 16) ^ ((n & 7) << 4));   // conflict-free 16B slot
    }

    const unsigned char* imgA = img + mb * (8 * ABUF);
    const int lds_u = wid * 2048;              // wave-uniform part of linear offset

    float f0[2][8], f1[2][8], f2[2][8];        // B in flight, 3-deep rotation
    float bsq[2] = {0.f, 0.f};

#define WAITV_(N) asm volatile("s_waitcnt vmcnt(" #N ")" ::: "memory")
#define WAITV(N) WAITV_(N)
#define SB() __builtin_amdgcn_sched_barrier(0)

#define LOAD_B(FR, T) do {                                                     \
    _Pragma("unroll")                                                          \
    for (int i = 0; i < 2; ++i) {                                              \
        const float* p = W + b_go[i] + (size_t)(T) * (BK * CC);                \
        _Pragma("unroll")                                                      \
        for (int j = 0; j < 8; ++j)                                            \
            FR[i][j] = p[(size_t)j * CC];                                      \
    } } while (0)

// pack 8 f32 -> 4 u32 (cvt_pk) + ONE ds_write_b128 per task; fuse column sumsq
#define PACK_WRITE(FR, T) do {                                                 \
    unsigned char* dst = bufB + ((T) & 1) * 16384;                             \
    _Pragma("unroll")                                                          \
    for (int i = 0; i < 2; ++i) {                                              \
        _Pragma("unroll")                                                      \
        for (int j = 0; j < 8; ++j)                                            \
            bsq[i] += FR[i][j] * FR[i][j];                                     \
        uint4 w;                                                               \
        asm("v_cvt_pk_bf16_f32 %0, %1, %2" : "=v"(w.x) : "v"(FR[i][0]), "v"(FR[i][1])); \
        asm("v_cvt_pk_bf16_f32 %0, %1, %2" : "=v"(w.y) : "v"(FR[i][2]), "v"(FR[i][3])); \
        asm("v_cvt_pk_bf16_f32 %0, %1, %2" : "=v"(w.z) : "v"(FR[i][4]), "v"(FR[i][5])); \
        asm("v_cvt_pk_bf16_f32 %0, %1, %2" : "=v"(w.w) : "v"(FR[i][6]), "v"(FR[i][7])); \
        *(uint4*)(dst + b_ld[i]) = w;                                          \
    } } while (0)

#define GLL_A(T) do {                                                          \
    unsigned char* A_nxt = bufA + ((T) & 1) * ABUF;                            \
    const unsigned char* gsrc = imgA + (T) * ABUF;                             \
    gll16(gsrc + lds_u + lane * 16, A_nxt + lds_u);                            \
    gll16(gsrc + lds_u + 1024 + lane * 16, A_nxt + lds_u + 1024);              \
    } while (0)

#define COMPUTE(T) do {                                                        \
    const unsigned char* A_cur = bufA + ((T) & 1) * ABUF;                      \
    const unsigned char* B_cur = bufB + ((T) & 1) * 16384;                     \
    __builtin_amdgcn_s_setprio(1);                                             \
    _Pragma("unroll")                                                          \
    for (int ks = 0; ks < 2; ++ks) {                                           \
        bf16x8 af[4], bfr[2];                                                  \
        _Pragma("unroll")                                                      \
        for (int mf = 0; mf < 4; ++mf)                                         \
            af[mf] = *(const bf16x8*)(A_cur + swz(wm * 64 + mf * 16 + lr, ks * 64 + lg * 16)); \
        _Pragma("unroll")                                                      \
        for (int nf = 0; nf < 2; ++nf)                                         \
            bfr[nf] = *(const bf16x8*)(B_cur + swz(wn * 32 + nf * 16 + lr, ks * 64 + lg * 16)); \
        _Pragma("unroll")                                                      \
        for (int mf = 0; mf < 4; ++mf)                                         \
            _Pragma("unroll")                                                  \
            for (int nf = 0; nf < 2; ++nf)                                     \
                acc[mf][nf] = __builtin_amdgcn_mfma_f32_16x16x32_bf16(         \
                    bfr[nf], af[mf], acc[mf][nf], 0, 0, 0);                    \
    }                                                                          \
    __builtin_amdgcn_s_setprio(0);                                             \
    } while (0)

// iter body: FP holds B(T+1) (packed now, loaded at T-2 -> no wait), FN <- B(T+3)
#define KBODY(T, FP, FN) do {                                                  \
    if ((T) + 1 < KSTEPS) GLL_A((T) + 1);                                      \
    SB();                                                                      \
    COMPUTE(T);                                                                \
    SB();                                                                      \
    if ((T) + 1 < KSTEPS) PACK_WRITE(FP, (T) + 1);                             \
    if ((T) + 3 < KSTEPS) LOAD_B(FN, (T) + 3);                                 \
    SB();                                                                      \
    if ((T) + 1 < KSTEPS) {                                                    \
        if ((T) + 3 < KSTEPS) { WAITV(16); } else { WAITV(0); }                \
        SB();                                                                  \
        asm volatile("s_waitcnt lgkmcnt(0)" ::: "memory"); SB();               \
        __builtin_amdgcn_s_barrier(); SB();                                    \
    } } while (0)

    f32x4 acc[4][2];
    #pragma unroll
    for (int mf = 0; mf < 4; ++mf)
        #pragma unroll
        for (int nf = 0; nf < 2; ++nf)
            acc[mf][nf] = (f32x4)0.f;

    // ---- prologue: B(0):16, gll(0):2, B(1):16; pack B(0) (vmcnt 18); B(2):16;
    //      drain glls (vmcnt 32, leaves B(1)+B(2) in flight through the barrier) ----
    LOAD_B(f0, 0);
    GLL_A(0);
    LOAD_B(f1, 1);
    SB();
    PACK_WRITE(f0, 0);                     // auto wait ~vmcnt(18): drains B(0) only
    LOAD_B(f2, 2);
    SB();
    WAITV(32); SB();                       // drain gll(0); B(1):16 + B(2):16 ride on
    asm volatile("s_waitcnt lgkmcnt(0)" ::: "memory"); SB();
    __builtin_amdgcn_s_barrier(); SB();

    KBODY(0, f1, f0);                      // pack B1, load B3->f0
    KBODY(1, f2, f1);                      // pack B2, load B4->f1
    KBODY(2, f0, f2);                      // pack B3, load B5->f2
    KBODY(3, f1, f0);                      // pack B4, load B6->f0
    KBODY(4, f2, f1);                      // pack B5, load B7->f1
    KBODY(5, f0, f2);                      // pack B6
    KBODY(6, f1, f0);                      // pack B7
    KBODY(7, f2, f1);                      // compute only

    // ---- deterministic column-norm reduction (reuse bufB) ----
    __syncthreads();
    float* part = (float*)bufB;                // [8][128] floats = 4KB
    #pragma unroll
    for (int i = 0; i < 2; ++i)
        part[tid + i * 512] = bsq[i];          // slot = o*128+n, unique owner
    __syncthreads();
    if (tid < BN) {
        float s = 0.f;
        #pragma unroll
        for (int o = 0; o < 8; ++o)
            s += part[o * BN + tid];           // fixed order -> deterministic
        rn[tid] = rsqrtf(fmaxf(s, 1e-12f));
    }
    __syncthreads();

    // ---- epilogue: LDS-staged -> 512B-aligned full-sector non-temporal stores ----
    float* stag = (float*)bufA;                // 32 rows x 132 floats = 16.9KB
    #pragma unroll
    for (int rd = 0; rd < 4; ++rd) {
        if (wm == (rd >> 1)) {
            #pragma unroll
            for (int f = 0; f < 2; ++f) {
                const int mf = (rd & 1) * 2 + f;
                const int ml = f * 16 + lr;
                #pragma unroll
                for (int nf = 0; nf < 2; ++nf) {
                    const int nl = wn * 32 + nf * 16 + lg * 4;
                    const f32x4 rn4 = *(const f32x4*)(rn + nl);
                    f32x4 o;
                    #pragma unroll
                    for (int r = 0; r < 4; ++r)
                        o[r] = acc[mf][nf][r] * rn4[r];
                    *(f32x4*)(stag + ml * 132 + nl) = o;
                }
            }
        }
        __syncthreads();
        #pragma unroll
        for (int j = tid; j < 1024; j += 512) {
            const int m = j >> 5;
            const int n = (j & 31) * 4;
            if (N0 + n + 4 <= CC) {
                f32x4 o = *(const f32x4*)(stag + m * 132 + n);
                __builtin_nontemporal_store(o,
                    (f32x4*)(out + (size_t)(M0 + rd * 32 + m) * CC + N0 + n));
            }
        }
        __syncthreads();
    }
}

// ---------------- K3: margin fixup at label positions ----------------
__global__ __launch_bounds__(512) void k_fix(const int* __restrict__ lab,
                                             float* __restrict__ out) {
    const int b = threadIdx.x;
    const int c = lab[b];
    const size_t idx = (size_t)b * CC + c;
    float t = out[idx];
    t = fminf(fmaxf(t, -1.f), 1.f);
    float th = acosf(t) + MARGIN2;
    th = fminf(th, PI_F);              // min(t, t + (pi - stopgrad(t))) value-wise
    out[idx] = cosf(th);               // M3 == 0: no additive term
}

extern "C" void kernel_launch(void* const* d_in, const int* in_sizes, int n_in,
                              void* d_out, int out_size, void* d_ws, size_t ws_size,
                              hipStream_t stream) {
    const float* x   = (const float*)d_in[0];
    const float* W   = (const float*)d_in[1];
    const int*   lab = (const int*)d_in[2];
    float* out = (float*)d_out;

    unsigned char* img = (unsigned char*)d_ws;   // 512KB pre-swizzled xn images

    k_norm_x<<<dim3(BB / 4), dim3(256), 0, stream>>>(x, img);
    k_gemm<<<dim3(GRID), dim3(512), 0, stream>>>(img, W, out);
    k_fix<<<dim3(1), dim3(512), 0, stream>>>(lab, out);
}

// Round 16
// 103.983 us; speedup vs baseline: 2.4871x; 1.0783x over previous
//
#include <hip/hip_runtime.h>
#include <math.h>

#define BB 512       // batch rows (M)
#define DD 512       // depth (K)
#define CC 100000    // classes (N)
#define MARGIN2 0.5f
#define PI_F 3.14159265358979323846f

#define BM 128
#define BN 128
#define BK 64
#define KSTEPS (DD / BK)     // 8
#define NPAN 782             // ceil(100000/128), last panel 32 cols
#define GRID (4 * NPAN)      // 3128 = 8 * 391 exactly

typedef __bf16 bf16x8 __attribute__((ext_vector_type(8)));
typedef float f32x4 __attribute__((ext_vector_type(4)));

static __device__ __forceinline__ unsigned short f2bf(float f) {
    union { float f; unsigned u; } v; v.f = f;
    unsigned r = v.u + 0x7FFFu + ((v.u >> 16) & 1u);   // round-to-nearest-even
    return (unsigned short)(r >> 16);
}

// swizzled LDS byte offset for row-major [row][64 x bf16] tiles (row stride 128B)
static __device__ __forceinline__ int swz(int row, int kbyte) {
    return row * 128 + (kbyte ^ ((row & 7) << 4));
}

// async global->LDS, 16B per lane; LDS dest = wave-uniform base + lane*16 (HW rule)
static __device__ __forceinline__ void gll16(const unsigned char* g, unsigned char* l) {
    __builtin_amdgcn_global_load_lds(
        (const __attribute__((address_space(1))) void*)g,
        (__attribute__((address_space(3))) void*)l, 16, 0, 0);
}

// ---------------- K1: row-normalize x -> bf16, PRE-SWIZZLED A images ----------------
// Image layout for BM=128: img[(mb*8 + t)*16384 + swz(lrow, c8*16) + sub*8],
// mb = row>>7, lrow = row&127 -> gemm's linear global_load_lds reproduces the
// swizzled Ash layout exactly (m173 pattern).
__global__ __launch_bounds__(256) void k_norm_x(const float* __restrict__ x,
                                                unsigned char* __restrict__ img) {
    const int lane = threadIdx.x & 63;
    const int row  = blockIdx.x * 4 + (threadIdx.x >> 6);
    const float* xr = x + (size_t)row * DD;
    float4 v0 = *(const float4*)(xr + lane * 4);
    float4 v1 = *(const float4*)(xr + lane * 4 + 256);
    float s = v0.x*v0.x + v0.y*v0.y + v0.z*v0.z + v0.w*v0.w
            + v1.x*v1.x + v1.y*v1.y + v1.z*v1.z + v1.w*v1.w;
    #pragma unroll
    for (int m = 32; m; m >>= 1) s += __shfl_xor(s, m, 64);
    float rs = rsqrtf(fmaxf(s, 1e-12f));
    ushort4 o0, o1;
    o0.x = f2bf(v0.x * rs); o0.y = f2bf(v0.y * rs);
    o0.z = f2bf(v0.z * rs); o0.w = f2bf(v0.w * rs);
    o1.x = f2bf(v1.x * rs); o1.y = f2bf(v1.y * rs);
    o1.z = f2bf(v1.z * rs); o1.w = f2bf(v1.w * rs);

    const int mb   = row >> 7;            // which 128-row M block (0..3)
    const int lrow = row & 127;
    const int k0   = lane * 4;            // v0 covers k0..k0+3; v1 covers k0+256..
    const int t0   = k0 >> 6;             // 0..3 (v1 -> t0+4)
    const int c8   = (k0 >> 3) & 7;       // 16B chunk within 128B row
    const int sub  = (k0 >> 2) & 1;       // 8B half of the chunk
    const int base = (mb * 8 + t0) * 16384 + lrow * 128
                   + ((c8 * 16) ^ ((lrow & 7) << 4)) + sub * 8;
    *(ushort4*)(img + base)         = o0;
    *(ushort4*)(img + base + 65536) = o1;    // t0+4 image (4 * 16384)
}

// ---------------- K2: bf16 MFMA GEMM, 128x128, open-scheduled pipelined loop ----
// R15 structure (conflict-free B staging, depth-3 B, gll-A) with the intra-body
// sched_barrier walls REMOVED: GLL/LOAD issue at top of iter, COMPUTE + PACK form
// one scheduling region the compiler interleaves (m196: fine interleave is the
// lever; coarse phase-split hurts). SBs remain only around waitcnt/barrier.
// FIFO per iter: [... B(t+2):16][gll(t+1):2][B(t+3):16] -> end-of-iter WAITV(16)
// drains B(t+2)(arrived)+gll, leaves B(t+3) riding the barrier. Max 34 in flight.
#define ABUF 16384
#define LDSZ (2 * ABUF + 2 * 16384 + 512)   // 66048 -> 2 blocks/CU

__global__ __launch_bounds__(512, 4) void k_gemm(const unsigned char* __restrict__ img,
                                                 const float* __restrict__ W,
                                                 float* __restrict__ out) {
    __shared__ __align__(16) unsigned char LDS[LDSZ];
    unsigned char* bufA = LDS;                  // 2 x 16KB
    unsigned char* bufB = LDS + 2 * ABUF;       // 2 x 16KB
    float* rn = (float*)(LDS + 2 * ABUF + 32768);

    const int tid = threadIdx.x;
    const int bid = blockIdx.x;

    // bijective XCD swizzle: 3128 = 8*391; 4 mb-sharers of a W panel -> same XCD L2
    const int v  = (bid & 7) * 391 + (bid >> 3);
    const int mb = v & 3;
    const int nb = v >> 2;
    const int M0 = mb * BM;
    const int N0 = nb * BN;

    const int lane = tid & 63;
    const int wid  = tid >> 6;     // 0..7
    const int wm = wid >> 2;       // 0..1 -> 64 rows each
    const int wn = wid & 3;        // 0..3 -> 32 cols each
    const int lr = lane & 15;
    const int lg = lane >> 4;

    // ---- B staging tasks: 2 per thread; s = o*128 + n (o = k-octet 0..7) ----
    int b_go[2], b_ld[2];
    #pragma unroll
    for (int i = 0; i < 2; ++i) {
        int s  = tid + i * 512;
        int n  = s & 127;
        int o  = s >> 7;                       // k-octet
        int col = N0 + n;
        col = col < CC ? col : CC - 1;         // tail-panel clamp (dead cols)
        b_go[i] = o * 8 * CC + col;
        b_ld[i] = n * 128 + ((o * 16) ^ ((n & 7) << 4));   // conflict-free 16B slot
    }

    const unsigned char* imgA = img + mb * (8 * ABUF);
    const int lds_u = wid * 2048;              // wave-uniform part of linear offset

    float f0[2][8], f1[2][8], f2[2][8];        // B in flight, 3-deep rotation
    float bsq[2] = {0.f, 0.f};

#define WAITV_(N) asm volatile("s_waitcnt vmcnt(" #N ")" ::: "memory")
#define WAITV(N) WAITV_(N)
#define SB() __builtin_amdgcn_sched_barrier(0)

#define LOAD_B(FR, T) do {                                                     \
    _Pragma("unroll")                                                          \
    for (int i = 0; i < 2; ++i) {                                              \
        const float* p = W + b_go[i] + (size_t)(T) * (BK * CC);                \
        _Pragma("unroll")                                                      \
        for (int j = 0; j < 8; ++j)                                            \
            FR[i][j] = p[(size_t)j * CC];                                      \
    } } while (0)

// pack 8 f32 -> 4 u32 (cvt_pk) + ONE ds_write_b128 per task; fuse column sumsq
#define PACK_WRITE(FR, T) do {                                                 \
    unsigned char* dst = bufB + ((T) & 1) * 16384;                             \
    _Pragma("unroll")                                                          \
    for (int i = 0; i < 2; ++i) {                                              \
        _Pragma("unroll")                                                      \
        for (int j = 0; j < 8; ++j)                                            \
            bsq[i] += FR[i][j] * FR[i][j];                                     \
        uint4 w;                                                               \
        asm("v_cvt_pk_bf16_f32 %0, %1, %2" : "=v"(w.x) : "v"(FR[i][0]), "v"(FR[i][1])); \
        asm("v_cvt_pk_bf16_f32 %0, %1, %2" : "=v"(w.y) : "v"(FR[i][2]), "v"(FR[i][3])); \
        asm("v_cvt_pk_bf16_f32 %0, %1, %2" : "=v"(w.z) : "v"(FR[i][4]), "v"(FR[i][5])); \
        asm("v_cvt_pk_bf16_f32 %0, %1, %2" : "=v"(w.w) : "v"(FR[i][6]), "v"(FR[i][7])); \
        *(uint4*)(dst + b_ld[i]) = w;                                          \
    } } while (0)

#define GLL_A(T) do {                                                          \
    unsigned char* A_nxt = bufA + ((T) & 1) * ABUF;                            \
    const unsigned char* gsrc = imgA + (T) * ABUF;                             \
    gll16(gsrc + lds_u + lane * 16, A_nxt + lds_u);                            \
    gll16(gsrc + lds_u + 1024 + lane * 16, A_nxt + lds_u + 1024);              \
    } while (0)

#define COMPUTE(T) do {                                                        \
    const unsigned char* A_cur = bufA + ((T) & 1) * ABUF;                      \
    const unsigned char* B_cur = bufB + ((T) & 1) * 16384;                     \
    __builtin_amdgcn_s_setprio(1);                                             \
    _Pragma("unroll")                                                          \
    for (int ks = 0; ks < 2; ++ks) {                                           \
        bf16x8 af[4], bfr[2];                                                  \
        _Pragma("unroll")                                                      \
        for (int mf = 0; mf < 4; ++mf)                                         \
            af[mf] = *(const bf16x8*)(A_cur + swz(wm * 64 + mf * 16 + lr, ks * 64 + lg * 16)); \
        _Pragma("unroll")                                                      \
        for (int nf = 0; nf < 2; ++nf)                                         \
            bfr[nf] = *(const bf16x8*)(B_cur + swz(wn * 32 + nf * 16 + lr, ks * 64 + lg * 16)); \
        _Pragma("unroll")                                                      \
        for (int mf = 0; mf < 4; ++mf)                                         \
            _Pragma("unroll")                                                  \
            for (int nf = 0; nf < 2; ++nf)                                     \
                acc[mf][nf] = __builtin_amdgcn_mfma_f32_16x16x32_bf16(         \
                    bfr[nf], af[mf], acc[mf][nf], 0, 0, 0);                    \
    }                                                                          \
    __builtin_amdgcn_s_setprio(0);                                             \
    } while (0)

// iter body: issue-early gll+loads; open region for COMPUTE+PACK interleave.
// FP = B(T+1) regs (packed now, loaded at T-2: retired, no wait), FN <- B(T+3).
#define KBODY(T, FP, FN) do {                                                  \
    if ((T) + 1 < KSTEPS) GLL_A((T) + 1);        /* gll BEFORE loads (FIFO) */ \
    if ((T) + 3 < KSTEPS) LOAD_B(FN, (T) + 3);                                 \
    COMPUTE(T);                                                                \
    if ((T) + 1 < KSTEPS) PACK_WRITE(FP, (T) + 1);                             \
    SB();                                                                      \
    if ((T) + 1 < KSTEPS) {                                                    \
        if ((T) + 3 < KSTEPS) { WAITV(16); } else { WAITV(0); }                \
        SB();                                                                  \
        asm volatile("s_waitcnt lgkmcnt(0)" ::: "memory"); SB();               \
        __builtin_amdgcn_s_barrier(); SB();                                    \
    } } while (0)

    f32x4 acc[4][2];
    #pragma unroll
    for (int mf = 0; mf < 4; ++mf)
        #pragma unroll
        for (int nf = 0; nf < 2; ++nf)
            acc[mf][nf] = (f32x4)0.f;

    // ---- prologue: B0, gll0, B1; pack B0 (auto vmcnt 18); B2; drain gll (32) ----
    LOAD_B(f0, 0);
    GLL_A(0);
    LOAD_B(f1, 1);
    PACK_WRITE(f0, 0);                     // auto counted wait: drains B0 only
    LOAD_B(f2, 2);
    SB();
    WAITV(32); SB();                       // drain gll0; B1:16 + B2:16 ride on
    asm volatile("s_waitcnt lgkmcnt(0)" ::: "memory"); SB();
    __builtin_amdgcn_s_barrier(); SB();

    KBODY(0, f1, f0);                      // pack B1, load B3->f0
    KBODY(1, f2, f1);                      // pack B2, load B4->f1
    KBODY(2, f0, f2);                      // pack B3, load B5->f2
    KBODY(3, f1, f0);                      // pack B4, load B6->f0
    KBODY(4, f2, f1);                      // pack B5, load B7->f1
    KBODY(5, f0, f2);                      // pack B6
    KBODY(6, f1, f0);                      // pack B7
    KBODY(7, f2, f1);                      // compute only

    // ---- deterministic column-norm reduction (reuse bufB) ----
    __syncthreads();
    float* part = (float*)bufB;                // [8][128] floats = 4KB
    #pragma unroll
    for (int i = 0; i < 2; ++i)
        part[tid + i * 512] = bsq[i];          // slot = o*128+n, unique owner
    __syncthreads();
    if (tid < BN) {
        float s = 0.f;
        #pragma unroll
        for (int o = 0; o < 8; ++o)
            s += part[o * BN + tid];           // fixed order -> deterministic
        rn[tid] = rsqrtf(fmaxf(s, 1e-12f));
    }
    __syncthreads();

    // ---- epilogue: LDS-staged -> 512B-aligned full-sector non-temporal stores ----
    float* stag = (float*)bufA;                // 32 rows x 132 floats = 16.9KB
    #pragma unroll
    for (int rd = 0; rd < 4; ++rd) {
        if (wm == (rd >> 1)) {
            #pragma unroll
            for (int f = 0; f < 2; ++f) {
                const int mf = (rd & 1) * 2 + f;
                const int ml = f * 16 + lr;
                #pragma unroll
                for (int nf = 0; nf < 2; ++nf) {
                    const int nl = wn * 32 + nf * 16 + lg * 4;
                    const f32x4 rn4 = *(const f32x4*)(rn + nl);
                    f32x4 o;
                    #pragma unroll
                    for (int r = 0; r < 4; ++r)
                        o[r] = acc[mf][nf][r] * rn4[r];
                    *(f32x4*)(stag + ml * 132 + nl) = o;
                }
            }
        }
        __syncthreads();
        #pragma unroll
        for (int j = tid; j < 1024; j += 512) {
            const int m = j >> 5;
            const int n = (j & 31) * 4;
            if (N0 + n + 4 <= CC) {
                f32x4 o = *(const f32x4*)(stag + m * 132 + n);
                __builtin_nontemporal_store(o,
                    (f32x4*)(out + (size_t)(M0 + rd * 32 + m) * CC + N0 + n));
            }
        }
        __syncthreads();
    }
}

// ---------------- K3: margin fixup at label positions ----------------
__global__ __launch_bounds__(512) void k_fix(const int* __restrict__ lab,
                                             float* __restrict__ out) {
    const int b = threadIdx.x;
    const int c = lab[b];
    const size_t idx = (size_t)b * CC + c;
    float t = out[idx];
    t = fminf(fmaxf(t, -1.f), 1.f);
    float th = acosf(t) + MARGIN2;
    th = fminf(th, PI_F);              // min(t, t + (pi - stopgrad(t))) value-wise
    out[idx] = cosf(th);               // M3 == 0: no additive term
}

extern "C" void kernel_launch(void* const* d_in, const int* in_sizes, int n_in,
                              void* d_out, int out_size, void* d_ws, size_t ws_size,
                              hipStream_t stream) {
    const float* x   = (const float*)d_in[0];
    const float* W   = (const float*)d_in[1];
    const int*   lab = (const int*)d_in[2];
    float* out = (float*)d_out;

    unsigned char* img = (unsigned char*)d_ws;   // 512KB pre-swizzled xn images

    k_norm_x<<<dim3(BB / 4), dim3(256), 0, stream>>>(x, img);
    k_gemm<<<dim3(GRID), dim3(512), 0, stream>>>(img, W, out);
    k_fix<<<dim3(1), dim3(512), 0, stream>>>(lab, out);
}

// Round 17
// 103.821 us; speedup vs baseline: 2.4910x; 1.0016x over previous
//
#include <hip/hip_runtime.h>
#include <math.h>

#define BB 512       // batch rows (M)
#define DD 512       // depth (K)
#define CC 100000    // classes (N)
#define MARGIN2 0.5f
#define PI_F 3.14159265358979323846f

#define BM 128
#define BN 128
#define BK 64
#define KSTEPS (DD / BK)     // 8
#define NPAN 782             // ceil(100000/128), last panel 32 cols
#define GRID (4 * NPAN)      // 3128 = 8 * 391 exactly

typedef __bf16 bf16x8 __attribute__((ext_vector_type(8)));
typedef float f32x4 __attribute__((ext_vector_type(4)));

static __device__ __forceinline__ unsigned short f2bf(float f) {
    union { float f; unsigned u; } v; v.f = f;
    unsigned r = v.u + 0x7FFFu + ((v.u >> 16) & 1u);   // round-to-nearest-even
    return (unsigned short)(r >> 16);
}

// swizzled LDS byte offset for row-major [row][64 x bf16] tiles (row stride 128B)
static __device__ __forceinline__ int swz(int row, int kbyte) {
    return row * 128 + (kbyte ^ ((row & 7) << 4));
}

// async global->LDS, 16B per lane; LDS dest = wave-uniform base + lane*16 (HW rule)
static __device__ __forceinline__ void gll16(const unsigned char* g, unsigned char* l) {
    __builtin_amdgcn_global_load_lds(
        (const __attribute__((address_space(1))) void*)g,
        (__attribute__((address_space(3))) void*)l, 16, 0, 0);
}

// ---------------- K1: row-normalize x -> bf16, PRE-SWIZZLED A images ----------------
// Image layout for BM=128: img[(mb*8 + t)*16384 + swz(lrow, c8*16) + sub*8],
// mb = row>>7, lrow = row&127 -> gemm's linear global_load_lds reproduces the
// swizzled Ash layout exactly (m173 pattern).
__global__ __launch_bounds__(256) void k_norm_x(const float* __restrict__ x,
                                                unsigned char* __restrict__ img) {
    const int lane = threadIdx.x & 63;
    const int row  = blockIdx.x * 4 + (threadIdx.x >> 6);
    const float* xr = x + (size_t)row * DD;
    float4 v0 = *(const float4*)(xr + lane * 4);
    float4 v1 = *(const float4*)(xr + lane * 4 + 256);
    float s = v0.x*v0.x + v0.y*v0.y + v0.z*v0.z + v0.w*v0.w
            + v1.x*v1.x + v1.y*v1.y + v1.z*v1.z + v1.w*v1.w;
    #pragma unroll
    for (int m = 32; m; m >>= 1) s += __shfl_xor(s, m, 64);
    float rs = rsqrtf(fmaxf(s, 1e-12f));
    ushort4 o0, o1;
    o0.x = f2bf(v0.x * rs); o0.y = f2bf(v0.y * rs);
    o0.z = f2bf(v0.z * rs); o0.w = f2bf(v0.w * rs);
    o1.x = f2bf(v1.x * rs); o1.y = f2bf(v1.y * rs);
    o1.z = f2bf(v1.z * rs); o1.w = f2bf(v1.w * rs);

    const int mb   = row >> 7;            // which 128-row M block (0..3)
    const int lrow = row & 127;
    const int k0   = lane * 4;            // v0 covers k0..k0+3; v1 covers k0+256..
    const int t0   = k0 >> 6;             // 0..3 (v1 -> t0+4)
    const int c8   = (k0 >> 3) & 7;       // 16B chunk within 128B row
    const int sub  = (k0 >> 2) & 1;       // 8B half of the chunk
    const int base = (mb * 8 + t0) * 16384 + lrow * 128
                   + ((c8 * 16) ^ ((lrow & 7) << 4)) + sub * 8;
    *(ushort4*)(img + base)         = o0;
    *(ushort4*)(img + base + 65536) = o1;    // t0+4 image (4 * 16384)
}

// ---------------- K2: bf16 MFMA GEMM + fused margin fixup ----------------------
// R16 open-scheduled pipeline (conflict-free B staging, depth-3 B, gll-A) plus:
// the ArcFace label fixup is fused into the epilogue. Each block owns rows
// M0..M0+127 x cols N0..N0+127 exclusively -> race-free. Labels loaded to LDS
// in the prologue; a tiny per-ROW pass (32 threads) patches the staged tile
// between staging and store, so the rare acos/cos never lands predicated in
// every store's path. k_fix kernel + launch eliminated.
#define ABUF 16384
#define LDSZ (2 * ABUF + 2 * 16384 + 512 + 512)   // 66560 -> 2 blocks/CU

__global__ __launch_bounds__(512, 4) void k_gemm(const unsigned char* __restrict__ img,
                                                 const float* __restrict__ W,
                                                 const int* __restrict__ lab,
                                                 float* __restrict__ out) {
    __shared__ __align__(16) unsigned char LDS[LDSZ];
    unsigned char* bufA = LDS;                  // 2 x 16KB
    unsigned char* bufB = LDS + 2 * ABUF;       // 2 x 16KB
    float* rn  = (float*)(LDS + 2 * ABUF + 32768);   // 512B
    int*   labs = (int*)(LDS + 2 * ABUF + 32768 + 512);  // 128 ints

    const int tid = threadIdx.x;
    const int bid = blockIdx.x;

    // bijective XCD swizzle: 3128 = 8*391; 4 mb-sharers of a W panel -> same XCD L2
    const int v  = (bid & 7) * 391 + (bid >> 3);
    const int mb = v & 3;
    const int nb = v >> 2;
    const int M0 = mb * BM;
    const int N0 = nb * BN;

    const int lane = tid & 63;
    const int wid  = tid >> 6;     // 0..7
    const int wm = wid >> 2;       // 0..1 -> 64 rows each
    const int wn = wid & 3;        // 0..3 -> 32 cols each
    const int lr = lane & 15;
    const int lg = lane >> 4;

    // ---- fetch this block's 128 labels first (waves 0-1; retires before B FIFO) ----
    if (tid < 128) labs[tid] = lab[M0 + tid];

    // ---- B staging tasks: 2 per thread; s = o*128 + n (o = k-octet 0..7) ----
    int b_go[2], b_ld[2];
    #pragma unroll
    for (int i = 0; i < 2; ++i) {
        int s  = tid + i * 512;
        int n  = s & 127;
        int o  = s >> 7;                       // k-octet
        int col = N0 + n;
        col = col < CC ? col : CC - 1;         // tail-panel clamp (dead cols)
        b_go[i] = o * 8 * CC + col;
        b_ld[i] = n * 128 + ((o * 16) ^ ((n & 7) << 4));   // conflict-free 16B slot
    }

    const unsigned char* imgA = img + mb * (8 * ABUF);
    const int lds_u = wid * 2048;              // wave-uniform part of linear offset

    float f0[2][8], f1[2][8], f2[2][8];        // B in flight, 3-deep rotation
    float bsq[2] = {0.f, 0.f};

#define WAITV_(N) asm volatile("s_waitcnt vmcnt(" #N ")" ::: "memory")
#define WAITV(N) WAITV_(N)
#define SB() __builtin_amdgcn_sched_barrier(0)

#define LOAD_B(FR, T) do {                                                     \
    _Pragma("unroll")                                                          \
    for (int i = 0; i < 2; ++i) {                                              \
        const float* p = W + b_go[i] + (size_t)(T) * (BK * CC);                \
        _Pragma("unroll")                                                      \
        for (int j = 0; j < 8; ++j)                                            \
            FR[i][j] = p[(size_t)j * CC];                                      \
    } } while (0)

// pack 8 f32 -> 4 u32 (cvt_pk) + ONE ds_write_b128 per task; fuse column sumsq
#define PACK_WRITE(FR, T) do {                                                 \
    unsigned char* dst = bufB + ((T) & 1) * 16384;                             \
    _Pragma("unroll")                                                          \
    for (int i = 0; i < 2; ++i) {                                              \
        _Pragma("unroll")                                                      \
        for (int j = 0; j < 8; ++j)                                            \
            bsq[i] += FR[i][j] * FR[i][j];                                     \
        uint4 w;                                                               \
        asm("v_cvt_pk_bf16_f32 %0, %1, %2" : "=v"(w.x) : "v"(FR[i][0]), "v"(FR[i][1])); \
        asm("v_cvt_pk_bf16_f32 %0, %1, %2" : "=v"(w.y) : "v"(FR[i][2]), "v"(FR[i][3])); \
        asm("v_cvt_pk_bf16_f32 %0, %1, %2" : "=v"(w.z) : "v"(FR[i][4]), "v"(FR[i][5])); \
        asm("v_cvt_pk_bf16_f32 %0, %1, %2" : "=v"(w.w) : "v"(FR[i][6]), "v"(FR[i][7])); \
        *(uint4*)(dst + b_ld[i]) = w;                                          \
    } } while (0)

#define GLL_A(T) do {                                                          \
    unsigned char* A_nxt = bufA + ((T) & 1) * ABUF;                            \
    const unsigned char* gsrc = imgA + (T) * ABUF;                             \
    gll16(gsrc + lds_u + lane * 16, A_nxt + lds_u);                            \
    gll16(gsrc + lds_u + 1024 + lane * 16, A_nxt + lds_u + 1024);              \
    } while (0)

#define COMPUTE(T) do {                                                        \
    const unsigned char* A_cur = bufA + ((T) & 1) * ABUF;                      \
    const unsigned char* B_cur = bufB + ((T) & 1) * 16384;                     \
    __builtin_amdgcn_s_setprio(1);                                             \
    _Pragma("unroll")                                                          \
    for (int ks = 0; ks < 2; ++ks) {                                           \
        bf16x8 af[4], bfr[2];                                                  \
        _Pragma("unroll")                                                      \
        for (int mf = 0; mf < 4; ++mf)                                         \
            af[mf] = *(const bf16x8*)(A_cur + swz(wm * 64 + mf * 16 + lr, ks * 64 + lg * 16)); \
        _Pragma("unroll")                                                      \
        for (int nf = 0; nf < 2; ++nf)                                         \
            bfr[nf] = *(const bf16x8*)(B_cur + swz(wn * 32 + nf * 16 + lr, ks * 64 + lg * 16)); \
        _Pragma("unroll")                                                      \
        for (int mf = 0; mf < 4; ++mf)                                         \
            _Pragma("unroll")                                                  \
            for (int nf = 0; nf < 2; ++nf)                                     \
                acc[mf][nf] = __builtin_amdgcn_mfma_f32_16x16x32_bf16(         \
                    bfr[nf], af[mf], acc[mf][nf], 0, 0, 0);                    \
    }                                                                          \
    __builtin_amdgcn_s_setprio(0);                                             \
    } while (0)

// iter body: issue-early gll+loads; open region for COMPUTE+PACK interleave.
// FP = B(T+1) regs (packed now, loaded at T-2: retired, no wait), FN <- B(T+3).
#define KBODY(T, FP, FN) do {                                                  \
    if ((T) + 1 < KSTEPS) GLL_A((T) + 1);        /* gll BEFORE loads (FIFO) */ \
    if ((T) + 3 < KSTEPS) LOAD_B(FN, (T) + 3);                                 \
    COMPUTE(T);                                                                \
    if ((T) + 1 < KSTEPS) PACK_WRITE(FP, (T) + 1);                             \
    SB();                                                                      \
    if ((T) + 1 < KSTEPS) {                                                    \
        if ((T) + 3 < KSTEPS) { WAITV(16); } else { WAITV(0); }                \
        SB();                                                                  \
        asm volatile("s_waitcnt lgkmcnt(0)" ::: "memory"); SB();               \
        __builtin_amdgcn_s_barrier(); SB();                                    \
    } } while (0)

    f32x4 acc[4][2];
    #pragma unroll
    for (int mf = 0; mf < 4; ++mf)
        #pragma unroll
        for (int nf = 0; nf < 2; ++nf)
            acc[mf][nf] = (f32x4)0.f;

    // ---- prologue: B0, gll0, B1; pack B0 (auto counted); B2; drain gll (32) ----
    LOAD_B(f0, 0);
    GLL_A(0);
    LOAD_B(f1, 1);
    PACK_WRITE(f0, 0);                     // auto counted wait: drains B0 only
    LOAD_B(f2, 2);
    SB();
    WAITV(32); SB();                       // drain gll0 (+lab); B1:16 + B2:16 ride on
    asm volatile("s_waitcnt lgkmcnt(0)" ::: "memory"); SB();
    __builtin_amdgcn_s_barrier(); SB();

    KBODY(0, f1, f0);                      // pack B1, load B3->f0
    KBODY(1, f2, f1);                      // pack B2, load B4->f1
    KBODY(2, f0, f2);                      // pack B3, load B5->f2
    KBODY(3, f1, f0);                      // pack B4, load B6->f0
    KBODY(4, f2, f1);                      // pack B5, load B7->f1
    KBODY(5, f0, f2);                      // pack B6
    KBODY(6, f1, f0);                      // pack B7
    KBODY(7, f2, f1);                      // compute only

    // ---- deterministic column-norm reduction (reuse bufB) ----
    __syncthreads();
    float* part = (float*)bufB;                // [8][128] floats = 4KB
    #pragma unroll
    for (int i = 0; i < 2; ++i)
        part[tid + i * 512] = bsq[i];          // slot = o*128+n, unique owner
    __syncthreads();
    if (tid < BN) {
        float s = 0.f;
        #pragma unroll
        for (int o = 0; o < 8; ++o)
            s += part[o * BN + tid];           // fixed order -> deterministic
        rn[tid] = rsqrtf(fmaxf(s, 1e-12f));
    }
    __syncthreads();

    // ---- epilogue: stage -> per-row label fixup -> sector-aligned NT stores ----
    float* stag = (float*)bufA;                // 32 rows x 132 floats = 16.9KB
    #pragma unroll
    for (int rd = 0; rd < 4; ++rd) {
        if (wm == (rd >> 1)) {
            #pragma unroll
            for (int f = 0; f < 2; ++f) {
                const int mf = (rd & 1) * 2 + f;
                const int ml = f * 16 + lr;
                #pragma unroll
                for (int nf = 0; nf < 2; ++nf) {
                    const int nl = wn * 32 + nf * 16 + lg * 4;
                    const f32x4 rn4 = *(const f32x4*)(rn + nl);
                    f32x4 o;
                    #pragma unroll
                    for (int r = 0; r < 4; ++r)
                        o[r] = acc[mf][nf][r] * rn4[r];
                    *(f32x4*)(stag + ml * 132 + nl) = o;
                }
            }
        }
        __syncthreads();
        // fused margin fixup: one thread per staged row (32 rows), rare branch
        if (tid < 32) {
            const int c   = labs[rd * 32 + tid];   // this row's label column
            const int off = c - N0;
            if (off >= 0 && off < BN) {
                float val = stag[tid * 132 + off];
                val = fminf(fmaxf(val, -1.f), 1.f);
                float th = fminf(acosf(val) + MARGIN2, PI_F);
                stag[tid * 132 + off] = cosf(th);  // M3 == 0
            }
        }
        __syncthreads();
        #pragma unroll
        for (int j = tid; j < 1024; j += 512) {
            const int m = j >> 5;
            const int n = (j & 31) * 4;
            if (N0 + n + 4 <= CC) {
                f32x4 o = *(const f32x4*)(stag + m * 132 + n);
                __builtin_nontemporal_store(o,
                    (f32x4*)(out + (size_t)(M0 + rd * 32 + m) * CC + N0 + n));
            }
        }
        __syncthreads();
    }
}

extern "C" void kernel_launch(void* const* d_in, const int* in_sizes, int n_in,
                              void* d_out, int out_size, void* d_ws, size_t ws_size,
                              hipStream_t stream) {
    const float* x   = (const float*)d_in[0];
    const float* W   = (const float*)d_in[1];
    const int*   lab = (const int*)d_in[2];
    float* out = (float*)d_out;

    unsigned char* img = (unsigned char*)d_ws;   // 512KB pre-swizzled xn images

    k_norm_x<<<dim3(BB / 4), dim3(256), 0, stream>>>(x, img);
    k_gemm<<<dim3(GRID), dim3(512), 0, stream>>>(img, W, lab, out);
}